// Round 12
// baseline (22.669 us; speedup 1.0000x reference)
//
#include <hip/hip_runtime.h>

typedef short  bf16x8 __attribute__((ext_vector_type(8)));   // 8 bf16 (4 VGPRs)
typedef float  f32x16 __attribute__((ext_vector_type(16)));  // MFMA 32x32 accumulator
typedef unsigned int uint4v __attribute__((ext_vector_type(4)));

constexpr int BLK = 256;              // 4 waves
constexpr int PTS_PER_BLOCK = 512;    // 4 waves x 2 iters x 64 lanes

#define LOG2E 1.4426950408889634f
#define LN2   0.6931471805599453f

__device__ __forceinline__ float fast_rcp(float x)  { return __builtin_amdgcn_rcpf(x); }
__device__ __forceinline__ float fast_exp2(float x) { return __builtin_amdgcn_exp2f(x); }
__device__ __forceinline__ float fast_log2(float x) { return __builtin_amdgcn_logf(x); }
__device__ __forceinline__ float max0(float x) { return fmaxf(x, 0.0f); }
__device__ __forceinline__ float min0(float x) { return fminf(x, 0.0f); }

// v_cvt_pk_bf16_f32: dst.lo = bf16(lo), dst.hi = bf16(hi)  (RNE)
__device__ __forceinline__ unsigned cvt_pk_bf16(float lo, float hi) {
    unsigned r;
    asm("v_cvt_pk_bf16_f32 %0, %1, %2" : "=v"(r) : "v"(lo), "v"(hi));
    return r;
}
__device__ __forceinline__ float bperm_f(int src_lane, float v) {
    int r = __builtin_amdgcn_ds_bpermute(src_lane << 2, __builtin_bit_cast(int, v));
    return __builtin_bit_cast(float, r);
}
__device__ __forceinline__ unsigned bperm_u(int src_lane, unsigned v) {
    return (unsigned)__builtin_amdgcn_ds_bpermute(src_lane << 2, (int)v);
}

// ---------- scalar activations (round-6 proven forms) ----------
template<int A> __device__ __forceinline__ float act_fn(float z);
template<> __device__ __forceinline__ float act_fn<0>(float z) { return max0(z); }          // relu
template<> __device__ __forceinline__ float act_fn<1>(float z) {                            // tanh
    float e = fast_exp2(z * (2.0f * LOG2E));
    return fmaf(-2.0f, fast_rcp(e + 1.0f), 1.0f);
}
template<> __device__ __forceinline__ float act_fn<2>(float z) {                            // elu
    float em = fast_exp2(z * LOG2E) - 1.0f;
    return max0(z) + min0(em);
}
template<> __device__ __forceinline__ float act_fn<3>(float z) {                            // silu
    float d = fast_exp2(-z * LOG2E) + 1.0f;
    return z * fast_rcp(d);
}
template<> __device__ __forceinline__ float act_fn<4>(float z) {                            // gelu
    float d = fast_exp2(z * (-1.702f * LOG2E)) + 1.0f;
    return z * fast_rcp(d);
}
template<> __device__ __forceinline__ float act_fn<5>(float z) { return z; }                // none
template<> __device__ __forceinline__ float act_fn<6>(float z) {                            // selu
    const float sc = 1.0507009873554805f, scal = 1.7580993408473766f;
    float e = fast_exp2(z * LOG2E);
    float n = fmaf(scal, e, -scal);
    return fmaf(max0(z), sc, min0(n));
}
template<> __device__ __forceinline__ float act_fn<7>(float z) {                            // softplus
    float d = fast_exp2(-fabsf(z) * LOG2E) + 1.0f;
    return fmaf(LN2, fast_log2(d), max0(z));
}

// one expert-pair: 2 MFMAs (tile0 = pts 0-31, tile1 = pts 32-63), act + layer-2
template<int PAIR>
__device__ __forceinline__ void process_pair(bf16x8 a, bf16x8 b0, bf16x8 b1,
                                             const float (&w2)[16],
                                             float& S0, float& S1) {
    constexpr int E0 = PAIR * 2, E1 = PAIR * 2 + 1;
    f32x16 zc = (f32x16)(0.0f);
    f32x16 d0 = __builtin_amdgcn_mfma_f32_32x32x16_bf16(a, b0, zc, 0, 0, 0);
    f32x16 d1 = __builtin_amdgcn_mfma_f32_32x32x16_bf16(a, b1, zc, 0, 0, 0);
#pragma unroll
    for (int r = 0; r < 8; ++r) {          // rows 0-15 -> even expert
        S0 = fmaf(act_fn<E0>(d0[r]), w2[r], S0);
        S1 = fmaf(act_fn<E0>(d1[r]), w2[r], S1);
    }
#pragma unroll
    for (int r = 8; r < 16; ++r) {         // rows 16-31 -> odd expert
        S0 = fmaf(act_fn<E1>(d0[r]), w2[r], S0);
        S1 = fmaf(act_fn<E1>(d1[r]), w2[r], S1);
    }
}

__global__ __launch_bounds__(BLK)
void moe_kernel(const float* __restrict__ x,
                const float* __restrict__ W1,
                const float* __restrict__ b1,
                const float* __restrict__ W2,
                const float* __restrict__ b2,
                const float* __restrict__ ew,
                float* __restrict__ out, int npts) {
    const int lane = threadIdx.x & 63;
    const int wid  = threadIdx.x >> 6;
    const bool lo  = (lane < 32);

    // ---- A-fragments: weights as A (32 h-rows x 16 k), one per expert-pair ----
    // lane: row = lane&31 (h), k = (lane>>5)*8 + j. Real k: 0=wre,1=wim,2=wam,3=b1.
    bf16x8 afrag[4];
#pragma unroll
    for (int pair = 0; pair < 4; ++pair) {
        const int h  = lane & 31;
        const int e  = pair * 2 + (h >> 4);
        const int hh = h & 15;
        const unsigned d0 = cvt_pk_bf16(W1[e * 48 + hh], W1[e * 48 + 16 + hh]);
        const unsigned d1 = cvt_pk_bf16(W1[e * 48 + 32 + hh], b1[e * 16 + hh]);
        uint4v u = { lo ? d0 : 0u, lo ? d1 : 0u, 0u, 0u };
        afrag[pair] = __builtin_bit_cast(bf16x8, u);
    }

    // ---- per-lane layer-2 weights (ew folded), matching D row layout ----
    const int hi4 = (lane >> 5) << 2;   // 4*hi
    float w2v[4][16];
#pragma unroll
    for (int pair = 0; pair < 4; ++pair) {
#pragma unroll
        for (int r = 0; r < 16; ++r) {
            const int row = (r & 3) + 8 * (r >> 2) + hi4;
            const int e   = pair * 2 + (row >> 4);
            w2v[pair][r] = W2[e * 16 + (row & 15)] * ew[e];
        }
    }

    float bconst = 0.0f;
#pragma unroll
    for (int i = 0; i < 8; ++i) bconst = fmaf(ew[i], b2[i], bconst);
    const float ewA = ew[8], ewM = ew[9], ewS = ew[10], ewC = ew[11];

#pragma unroll
    for (int it = 0; it < 2; ++it) {
        const int wavebase = (blockIdx.x * 4 + wid) * 128 + it * 64;
        const int pt = wavebase + lane;
        const bool ok = (pt < npts);

        float2 v = ok ? reinterpret_cast<const float2*>(x)[pt] : make_float2(0.f, 0.f);
        const float re = v.x, im = v.y;
        const float am = __builtin_amdgcn_sqrtf(fmaf(re, re, im * im));

        // analytic experts for the lane's own point
        const float INV2PI = 0.15915494309189535f;
        const float s  = am * INV2PI;
        float acc_an = fmaf(ewA, fabsf(re) + fabsf(im), bconst);
        acc_an = fmaf(ewM, am, acc_an);
        acc_an = fmaf(ewS, __builtin_amdgcn_sinf(s), acc_an);
        acc_an = fmaf(ewC, __builtin_amdgcn_cosf(s), acc_an);

        // ---- B-fragments: feats as B (16 k x 32 pts). col=lane&31, k=(lane>>5)*8+j ----
        const unsigned f0 = cvt_pk_bf16(re, im);
        const unsigned f1 = cvt_pk_bf16(am, 1.0f);      // k3 = 1.0 carries the bias
        uint4v b0u = { lo ? f0 : 0u, lo ? f1 : 0u, 0u, 0u };
        bf16x8 bfrag0 = __builtin_bit_cast(bf16x8, b0u);
        // tile1 (pts 32-63): pull partner lane's packed feats
        const unsigned f0s = bperm_u(lane ^ 32, f0);
        const unsigned f1s = bperm_u(lane ^ 32, f1);
        uint4v b1u = { lo ? f0s : 0u, lo ? f1s : 0u, 0u, 0u };
        bf16x8 bfrag1 = __builtin_bit_cast(bf16x8, b1u);

        float S0 = 0.0f, S1 = 0.0f;
        process_pair<0>(afrag[0], bfrag0, bfrag1, w2v[0], S0, S1);  // relu | tanh
        process_pair<1>(afrag[1], bfrag0, bfrag1, w2v[1], S0, S1);  // elu  | silu
        process_pair<2>(afrag[2], bfrag0, bfrag1, w2v[2], S0, S1);  // gelu | none
        process_pair<3>(afrag[3], bfrag0, bfrag1, w2v[3], S0, S1);  // selu | softplus

        // finish: each point's 32 h-values are split across lanes l and l^32
        S0 += bperm_f(lane ^ 32, S0);
        S1 += bperm_f(lane ^ 32, S1);

        const float tot = (lo ? S0 : S1) + acc_an;
        if (ok) out[pt] = tot;
    }
}

extern "C" void kernel_launch(void* const* d_in, const int* in_sizes, int n_in,
                              void* d_out, int out_size, void* d_ws, size_t ws_size,
                              hipStream_t stream) {
    const float* x  = (const float*)d_in[0];
    const float* W1 = (const float*)d_in[1];
    const float* b1 = (const float*)d_in[2];
    const float* W2 = (const float*)d_in[3];
    const float* b2 = (const float*)d_in[4];
    const float* ew = (const float*)d_in[5];
    float* out = (float*)d_out;

    const int npts = in_sizes[0] / 2;  // (B,S,C,2) -> B*S*C points
    const int blocks = (npts + PTS_PER_BLOCK - 1) / PTS_PER_BLOCK;
    hipLaunchKernelGGL(moe_kernel, dim3(blocks), dim3(BLK), 0, stream,
                       x, W1, b1, W2, b2, ew, out, npts);
}

// Round 14
// 20.484 us; speedup vs baseline: 1.1067x; 1.1067x over previous
//
#include <hip/hip_runtime.h>

typedef short  bf16x8 __attribute__((ext_vector_type(8)));   // 8 bf16 (4 VGPRs)
typedef float  f32x16 __attribute__((ext_vector_type(16)));  // MFMA 32x32 accumulator
typedef float  v2f    __attribute__((ext_vector_type(2)));
typedef unsigned int uint4v __attribute__((ext_vector_type(4)));

constexpr int BLK = 256;              // 4 waves
constexpr int PTS_PER_BLOCK = 512;    // 4 waves x 2 iters x 64 lanes

#define LOG2E 1.4426950408889634f
#define LN2   0.6931471805599453f

__device__ __forceinline__ float fast_rcp(float x)  { return __builtin_amdgcn_rcpf(x); }
__device__ __forceinline__ float fast_exp2(float x) { return __builtin_amdgcn_exp2f(x); }
__device__ __forceinline__ float fast_log2(float x) { return __builtin_amdgcn_logf(x); }

__device__ __forceinline__ v2f splat(float s) { return (v2f){s, s}; }
__device__ __forceinline__ v2f pk_fma(v2f a, v2f b, v2f c) {
    return __builtin_elementwise_fma(a, b, c);
}
__device__ __forceinline__ v2f pk_max0(v2f a) {
    return __builtin_elementwise_max(a, (v2f){0.0f, 0.0f});
}
__device__ __forceinline__ v2f pk_min0(v2f a) {
    return __builtin_elementwise_min(a, (v2f){0.0f, 0.0f});
}
__device__ __forceinline__ v2f pk_exp2(v2f t) { return (v2f){fast_exp2(t.x), fast_exp2(t.y)}; }
__device__ __forceinline__ v2f pk_rcp(v2f t)  { return (v2f){fast_rcp(t.x),  fast_rcp(t.y)};  }

// v_cvt_pk_bf16_f32: dst.lo = bf16(lo), dst.hi = bf16(hi)  (RNE)
__device__ __forceinline__ unsigned cvt_pk_bf16(float lo, float hi) {
    unsigned r;
    asm("v_cvt_pk_bf16_f32 %0, %1, %2" : "=v"(r) : "v"(lo), "v"(hi));
    return r;
}
__device__ __forceinline__ float bperm_f(int src_lane, float v) {
    int r = __builtin_amdgcn_ds_bpermute(src_lane << 2, __builtin_bit_cast(int, v));
    return __builtin_bit_cast(float, r);
}
__device__ __forceinline__ unsigned bperm_u(int src_lane, unsigned v) {
    return (unsigned)__builtin_amdgcn_ds_bpermute(src_lane << 2, (int)v);
}

// ---------- packed activations (round-6 proven forms) ----------
template<int A> __device__ __forceinline__ v2f act2(v2f z);
template<> __device__ __forceinline__ v2f act2<0>(v2f z) { return pk_max0(z); }             // relu
template<> __device__ __forceinline__ v2f act2<1>(v2f z) {                                  // tanh
    v2f e = pk_exp2(z * (2.0f * LOG2E));
    v2f r = pk_rcp(e + 1.0f);
    return pk_fma(splat(-2.0f), r, splat(1.0f));
}
template<> __device__ __forceinline__ v2f act2<2>(v2f z) {                                  // elu
    v2f em = pk_exp2(z * LOG2E) - 1.0f;
    return pk_max0(z) + pk_min0(em);
}
template<> __device__ __forceinline__ v2f act2<3>(v2f z) {                                  // silu
    v2f e = pk_exp2(z * (-LOG2E));
    return z * pk_rcp(e + 1.0f);
}
template<> __device__ __forceinline__ v2f act2<4>(v2f z) {                                  // gelu
    v2f e = pk_exp2(z * (-1.702f * LOG2E));
    return z * pk_rcp(e + 1.0f);
}
template<> __device__ __forceinline__ v2f act2<5>(v2f z) { return z; }                      // none
template<> __device__ __forceinline__ v2f act2<6>(v2f z) {                                  // selu
    const float sc   = 1.0507009873554805f;
    const float scal = 1.7580993408473766f;   // sc*alpha
    v2f e = pk_exp2(z * LOG2E);
    v2f n = pk_fma(splat(scal), e, splat(-scal));
    return pk_fma(pk_max0(z), splat(sc), pk_min0(n));
}
template<> __device__ __forceinline__ v2f act2<7>(v2f z) {                                  // softplus
    v2f a = __builtin_elementwise_abs(z) * (-LOG2E);
    v2f d = pk_exp2(a) + 1.0f;
    v2f l = (v2f){fast_log2(d.x), fast_log2(d.y)};
    return pk_fma(splat(LN2), l, pk_max0(z));
}

// one expert-pair: 2 MFMAs (tile0 = pts 0-31, tile1 = pts 32-63),
// acts + layer-2 PACKED over accumulator-reg pairs (regs 2q,2q+1 = rows row0,row0+1,
// same expert: regs 0-7 -> even expert, regs 8-15 -> odd expert, for both lane halves)
template<int PAIR>
__device__ __forceinline__ void process_pair(bf16x8 a, bf16x8 b0, bf16x8 b1,
                                             const v2f (&w2)[8],
                                             v2f& S0, v2f& S1) {
    constexpr int E0 = PAIR * 2, E1 = PAIR * 2 + 1;
    f32x16 zc = (f32x16)(0.0f);
    f32x16 d0 = __builtin_amdgcn_mfma_f32_32x32x16_bf16(a, b0, zc, 0, 0, 0);
    f32x16 d1 = __builtin_amdgcn_mfma_f32_32x32x16_bf16(a, b1, zc, 0, 0, 0);
#pragma unroll
    for (int q = 0; q < 4; ++q) {          // regs 0-7 -> even expert
        S0 = pk_fma(act2<E0>((v2f){d0[2*q], d0[2*q+1]}), w2[q], S0);
        S1 = pk_fma(act2<E0>((v2f){d1[2*q], d1[2*q+1]}), w2[q], S1);
    }
#pragma unroll
    for (int q = 4; q < 8; ++q) {          // regs 8-15 -> odd expert
        S0 = pk_fma(act2<E1>((v2f){d0[2*q], d0[2*q+1]}), w2[q], S0);
        S1 = pk_fma(act2<E1>((v2f){d1[2*q], d1[2*q+1]}), w2[q], S1);
    }
}

__global__ __launch_bounds__(BLK)
void moe_kernel(const float* __restrict__ x,
                const float* __restrict__ W1,
                const float* __restrict__ b1,
                const float* __restrict__ W2,
                const float* __restrict__ b2,
                const float* __restrict__ ew,
                float* __restrict__ out, int npts) {
    const int lane = threadIdx.x & 63;
    const int wid  = threadIdx.x >> 6;
    const bool lo  = (lane < 32);

    // ---- A-fragments: weights as A (32 h-rows x 16 k), one per expert-pair ----
    // lane: row = lane&31 (h), k = (lane>>5)*8 + j. Real k: 0=wre,1=wim,2=wam,3=b1.
    bf16x8 afrag[4];
#pragma unroll
    for (int pair = 0; pair < 4; ++pair) {
        const int h  = lane & 31;
        const int e  = pair * 2 + (h >> 4);
        const int hh = h & 15;
        const unsigned d0 = cvt_pk_bf16(W1[e * 48 + hh], W1[e * 48 + 16 + hh]);
        const unsigned d1 = cvt_pk_bf16(W1[e * 48 + 32 + hh], b1[e * 16 + hh]);
        uint4v u = { lo ? d0 : 0u, lo ? d1 : 0u, 0u, 0u };
        afrag[pair] = __builtin_bit_cast(bf16x8, u);
    }

    // ---- per-lane layer-2 weight pairs (ew folded), D-layout reg pairs (2q,2q+1) ----
    const int hi4 = (lane >> 5) << 2;   // 4*hi
    v2f w2v[4][8];
#pragma unroll
    for (int pair = 0; pair < 4; ++pair) {
#pragma unroll
        for (int q = 0; q < 8; ++q) {
            const int row0 = ((2 * q) & 3) + 8 * (q >> 1) + hi4;   // even row index
            const int e    = pair * 2 + (row0 >> 4);
            const int idx  = e * 16 + (row0 & 15);
            w2v[pair][q] = (v2f){W2[idx] * ew[e], W2[idx + 1] * ew[e]};
        }
    }

    float bconst = 0.0f;
#pragma unroll
    for (int i = 0; i < 8; ++i) bconst = fmaf(ew[i], b2[i], bconst);
    const float ewA = ew[8], ewM = ew[9], ewS = ew[10], ewC = ew[11];

#pragma unroll
    for (int it = 0; it < 2; ++it) {
        const int wavebase = (blockIdx.x * 4 + wid) * 128 + it * 64;
        const int pt = wavebase + lane;
        const bool ok = (pt < npts);

        float2 v = ok ? reinterpret_cast<const float2*>(x)[pt] : make_float2(0.f, 0.f);
        const float re = v.x, im = v.y;
        const float am = __builtin_amdgcn_sqrtf(fmaf(re, re, im * im));

        // analytic experts for the lane's own point
        const float INV2PI = 0.15915494309189535f;
        const float s  = am * INV2PI;
        float acc_an = fmaf(ewA, fabsf(re) + fabsf(im), bconst);
        acc_an = fmaf(ewM, am, acc_an);
        acc_an = fmaf(ewS, __builtin_amdgcn_sinf(s), acc_an);
        acc_an = fmaf(ewC, __builtin_amdgcn_cosf(s), acc_an);

        // ---- B-fragments: feats as B (16 k x 32 pts), MASKED exactly like R12 ----
        const unsigned f0 = cvt_pk_bf16(re, im);
        const unsigned f1 = cvt_pk_bf16(am, 1.0f);      // k3 = 1.0 carries the bias
        uint4v b0u = { lo ? f0 : 0u, lo ? f1 : 0u, 0u, 0u };
        bf16x8 bfrag0 = __builtin_bit_cast(bf16x8, b0u);
        // tile1 (pts 32-63): pull partner lane's packed feats
        const unsigned f0s = bperm_u(lane ^ 32, f0);
        const unsigned f1s = bperm_u(lane ^ 32, f1);
        uint4v b1u = { lo ? f0s : 0u, lo ? f1s : 0u, 0u, 0u };
        bf16x8 bfrag1 = __builtin_bit_cast(bf16x8, b1u);

        v2f S0v = (v2f){0.0f, 0.0f}, S1v = (v2f){0.0f, 0.0f};
        process_pair<0>(afrag[0], bfrag0, bfrag1, w2v[0], S0v, S1v);  // relu | tanh
        process_pair<1>(afrag[1], bfrag0, bfrag1, w2v[1], S0v, S1v);  // elu  | silu
        process_pair<2>(afrag[2], bfrag0, bfrag1, w2v[2], S0v, S1v);  // gelu | none
        process_pair<3>(afrag[3], bfrag0, bfrag1, w2v[3], S0v, S1v);  // selu | softplus

        // horizontal over the v2f lanes, then combine the two lane-halves
        float S0 = S0v.x + S0v.y;
        float S1 = S1v.x + S1v.y;
        S0 += bperm_f(lane ^ 32, S0);
        S1 += bperm_f(lane ^ 32, S1);

        const float tot = (lo ? S0 : S1) + acc_an;
        if (ok) out[pt] = tot;
    }
}

extern "C" void kernel_launch(void* const* d_in, const int* in_sizes, int n_in,
                              void* d_out, int out_size, void* d_ws, size_t ws_size,
                              hipStream_t stream) {
    const float* x  = (const float*)d_in[0];
    const float* W1 = (const float*)d_in[1];
    const float* b1 = (const float*)d_in[2];
    const float* W2 = (const float*)d_in[3];
    const float* b2 = (const float*)d_in[4];
    const float* ew = (const float*)d_in[5];
    float* out = (float*)d_out;

    const int npts = in_sizes[0] / 2;  // (B,S,C,2) -> B*S*C points
    const int blocks = (npts + PTS_PER_BLOCK - 1) / PTS_PER_BLOCK;
    hipLaunchKernelGGL(moe_kernel, dim3(blocks), dim3(BLK), 0, stream,
                       x, W1, b1, W2, b2, ew, out, npts);
}